// Round 1
// baseline (299.375 us; speedup 1.0000x reference)
//
#include <hip/hip_runtime.h>
#include <hip/hip_fp16.h>

typedef _Float16 f16;
typedef __attribute__((ext_vector_type(8))) _Float16 f16x8;
typedef __attribute__((ext_vector_type(4))) _Float16 f16x4;
typedef __attribute__((ext_vector_type(4))) float f32x4;

// ---------------------------------------------------------------------------
// Pre-pass: h (fp32) -> f16 copy in workspace. Halves gather bytes for the
// main kernel (0.8 GB instead of 1.6 GB of random row reads).
// ---------------------------------------------------------------------------
__global__ void cvt_h_f16(const float* __restrict__ h, f16* __restrict__ hf, int n4) {
    int stride = gridDim.x * blockDim.x;
    for (int i = blockIdx.x * blockDim.x + threadIdx.x; i < n4; i += stride) {
        float4 v = reinterpret_cast<const float4*>(h)[i];
        f16x4 o = { (f16)v.x, (f16)v.y, (f16)v.z, (f16)v.w };
        reinterpret_cast<f16x4*>(hf)[i] = o;
    }
}

// ---------------------------------------------------------------------------
// Fused edge-MLP kernel.
//   Tile: 64 edges/block, 4 waves. Wave w owns output cols [32w, 32w+32).
//   GEMM1: he[64x256] @ W1^T[256x128]  (W1 frags in regs: 16 frags/wave)
//   GEMM2: x1[64x128] @ W2^T[128x128]  (8 frags/wave)
//   Layer3 in fp32 VALU + shfl reduce.
// MFMA k-mapping: we use k = ks*32 + 8*(lane>>4) + j consistently for BOTH
// A and B fragments; since A/B lane layouts are symmetric and MFMA sums over
// k, any consistent bijection is exact. C/D layout: col=lane&15,
// row=4*(lane>>4)+reg (measured, m89).
// LDS tiles are 16B-chunk XOR-swizzled (ch ^= row&7) to avoid bank-column
// conflicts on ds_read_b128.
// ---------------------------------------------------------------------------
__global__ __launch_bounds__(256, 2)
void mlp_edges(const float* __restrict__ h32, const f16* __restrict__ hf, int useF16,
               const int* __restrict__ srcI, const int* __restrict__ dstI,
               const float* __restrict__ W1, const float* __restrict__ b1,
               const float* __restrict__ W2, const float* __restrict__ b2,
               const float* __restrict__ W3, const float* __restrict__ b3,
               float* __restrict__ out, int E, int ntiles)
{
    __shared__ f16 heS[64 * 256];   // 32 KB, swizzled
    __shared__ f16 xS[64 * 128];    // 16 KB, swizzled
    __shared__ float sbuf[4][64];   // 1 KB

    const int tid = threadIdx.x;
    const int w = tid >> 6;        // wave 0..3
    const int l = tid & 63;
    const int g = l >> 4;          // 16-lane group 0..3
    const int c = l & 15;

    // ---- per-wave weight fragments (loaded once per block) ----
    f16x8 w1f[8][2];               // [kstep][ntile]  64 VGPR
    f16x8 w2f[4][2];               // 32 VGPR
    float b1c[2], b2c[2], w3c[2];
    #pragma unroll
    for (int nt = 0; nt < 2; ++nt) {
        const int n = w * 32 + nt * 16 + c;
        #pragma unroll
        for (int ks = 0; ks < 8; ++ks) {
            const float* p = W1 + n * 256 + ks * 32 + g * 8;
            f16x8 v;
            #pragma unroll
            for (int j = 0; j < 8; ++j) v[j] = (f16)p[j];
            w1f[ks][nt] = v;
        }
        #pragma unroll
        for (int ks = 0; ks < 4; ++ks) {
            const float* p = W2 + n * 128 + ks * 32 + g * 8;
            f16x8 v;
            #pragma unroll
            for (int j = 0; j < 8; ++j) v[j] = (f16)p[j];
            w2f[ks][nt] = v;
        }
        b1c[nt] = b1[n];
        b2c[nt] = b2[n];
        w3c[nt] = W3[n];           // W3 is [1,128] -> row 0
    }
    const float b3s = b3[0];

    for (int tile = blockIdx.x; tile < ntiles; tile += gridDim.x) {
        const int e0 = tile * 64;

        // ---- stage he tile: 128 gathered rows (64 src + 64 dst) ----
        {
            const int p = tid >> 1, q = tid & 1;   // 2 threads per row-gather
            const int m = p & 63;                  // edge within tile
            const bool isD = (p >= 64);
            const int e = e0 + m;
            int idx = 0;
            if (e < E) idx = isD ? dstI[e] : srcI[e];
            const int chb = (isD ? 16 : 0) + q * 8;   // 16B-chunk base within row
            if (useF16) {
                const f16x8* src = reinterpret_cast<const f16x8*>(hf + (size_t)idx * 128 + q * 64);
                #pragma unroll
                for (int j = 0; j < 8; ++j) {
                    const int ch = chb + j;
                    *reinterpret_cast<f16x8*>(&heS[m * 256 + (ch ^ (m & 7)) * 8]) = src[j];
                }
            } else {
                const float4* src = reinterpret_cast<const float4*>(h32 + (size_t)idx * 128 + q * 64);
                #pragma unroll
                for (int j = 0; j < 8; ++j) {
                    float4 a = src[2 * j], b = src[2 * j + 1];
                    f16x8 v = { (f16)a.x, (f16)a.y, (f16)a.z, (f16)a.w,
                                (f16)b.x, (f16)b.y, (f16)b.z, (f16)b.w };
                    const int ch = chb + j;
                    *reinterpret_cast<f16x8*>(&heS[m * 256 + (ch ^ (m & 7)) * 8]) = v;
                }
            }
        }
        __syncthreads();

        // ---- GEMM1: 64x256 @ 256x32(per wave) ----
        f32x4 acc1[4][2];
        #pragma unroll
        for (int mt = 0; mt < 4; ++mt) {
            acc1[mt][0] = (f32x4){0.f, 0.f, 0.f, 0.f};
            acc1[mt][1] = (f32x4){0.f, 0.f, 0.f, 0.f};
        }
        #pragma unroll
        for (int ks = 0; ks < 8; ++ks) {
            #pragma unroll
            for (int mt = 0; mt < 4; ++mt) {
                const int row = mt * 16 + c;
                const int ch = ks * 4 + g;
                f16x8 a = *reinterpret_cast<const f16x8*>(&heS[row * 256 + (ch ^ (row & 7)) * 8]);
                acc1[mt][0] = __builtin_amdgcn_mfma_f32_16x16x32_f16(a, w1f[ks][0], acc1[mt][0], 0, 0, 0);
                acc1[mt][1] = __builtin_amdgcn_mfma_f32_16x16x32_f16(a, w1f[ks][1], acc1[mt][1], 0, 0, 0);
            }
        }

        // ---- bias + ReLU + write x1 to LDS (f16) ----
        #pragma unroll
        for (int mt = 0; mt < 4; ++mt) {
            #pragma unroll
            for (int nt = 0; nt < 2; ++nt) {
                const int col = w * 32 + nt * 16 + c;
                const int ch = col >> 3, wi = col & 7;
                #pragma unroll
                for (int r = 0; r < 4; ++r) {
                    const int row = mt * 16 + 4 * g + r;
                    float x = acc1[mt][nt][r] + b1c[nt];
                    x = x > 0.f ? x : 0.f;
                    xS[row * 128 + (ch ^ (row & 7)) * 8 + wi] = (f16)x;
                }
            }
        }
        __syncthreads();

        // ---- GEMM2: 64x128 @ 128x32(per wave) ----
        f32x4 acc2[4][2];
        #pragma unroll
        for (int mt = 0; mt < 4; ++mt) {
            acc2[mt][0] = (f32x4){0.f, 0.f, 0.f, 0.f};
            acc2[mt][1] = (f32x4){0.f, 0.f, 0.f, 0.f};
        }
        #pragma unroll
        for (int ks = 0; ks < 4; ++ks) {
            #pragma unroll
            for (int mt = 0; mt < 4; ++mt) {
                const int row = mt * 16 + c;
                const int ch = ks * 4 + g;
                f16x8 a = *reinterpret_cast<const f16x8*>(&xS[row * 128 + (ch ^ (row & 7)) * 8]);
                acc2[mt][0] = __builtin_amdgcn_mfma_f32_16x16x32_f16(a, w2f[ks][0], acc2[mt][0], 0, 0, 0);
                acc2[mt][1] = __builtin_amdgcn_mfma_f32_16x16x32_f16(a, w2f[ks][1], acc2[mt][1], 0, 0, 0);
            }
        }

        // ---- layer 3 (fp32): relu(x2) . w3, reduce over 128 cols ----
        #pragma unroll
        for (int mt = 0; mt < 4; ++mt) {
            float part[4];
            #pragma unroll
            for (int r = 0; r < 4; ++r) {
                float s = 0.f;
                #pragma unroll
                for (int nt = 0; nt < 2; ++nt) {
                    float x = acc2[mt][nt][r] + b2c[nt];
                    x = x > 0.f ? x : 0.f;
                    s += x * w3c[nt];
                }
                part[r] = s;
            }
            // reduce across the 16 col-lanes of this group
            #pragma unroll
            for (int off = 1; off < 16; off <<= 1) {
                #pragma unroll
                for (int r = 0; r < 4; ++r) part[r] += __shfl_xor(part[r], off, 64);
            }
            if (c == 0) {
                #pragma unroll
                for (int r = 0; r < 4; ++r) sbuf[w][mt * 16 + 4 * g + r] = part[r];
            }
        }
        __syncthreads();

        if (tid < 64) {
            const int e = e0 + tid;
            if (e < E)
                out[e] = sbuf[0][tid] + sbuf[1][tid] + sbuf[2][tid] + sbuf[3][tid] + b3s;
        }
        // next staging only starts after all threads pass the sync above
    }
}

// ---------------------------------------------------------------------------
extern "C" void kernel_launch(void* const* d_in, const int* in_sizes, int n_in,
                              void* d_out, int out_size, void* d_ws, size_t ws_size,
                              hipStream_t stream) {
    const float* h  = (const float*)d_in[0];
    const int* srcI = (const int*)d_in[1];
    const int* dstI = (const int*)d_in[2];
    const float* W1 = (const float*)d_in[3];
    const float* b1 = (const float*)d_in[4];
    const float* W2 = (const float*)d_in[5];
    const float* b2 = (const float*)d_in[6];
    const float* W3 = (const float*)d_in[7];
    const float* b3 = (const float*)d_in[8];
    float* out = (float*)d_out;

    const int E = in_sizes[1];
    const int hElems = in_sizes[0];        // N_NODES * 128
    f16* hf = (f16*)d_ws;
    const int useF16 = (ws_size >= (size_t)hElems * sizeof(f16)) ? 1 : 0;

    if (useF16) {
        cvt_h_f16<<<2048, 256, 0, stream>>>(h, hf, hElems / 4);
    }

    const int ntiles = (E + 63) / 64;
    int grid = ntiles < 1024 ? ntiles : 1024;
    mlp_edges<<<grid, 256, 0, stream>>>(h, hf, useF16, srcI, dstI,
                                        W1, b1, W2, b2, W3, b3, out, E, ntiles);
}